// Round 7
// baseline (334.160 us; speedup 1.0000x reference)
//
#include <hip/hip_runtime.h>

typedef _Float16 half8 __attribute__((ext_vector_type(8)));
typedef _Float16 half4v __attribute__((ext_vector_type(4)));
typedef _Float16 half2v __attribute__((ext_vector_type(2)));
typedef float f32x4 __attribute__((ext_vector_type(4)));
typedef float f32x2 __attribute__((ext_vector_type(2)));
typedef int i32x4 __attribute__((ext_vector_type(4)));

#define CAP 32          // bucket capacity per output point (mean load = 5)
#define OVF_MAX 4096

// Y row-block internal permutation: position o' holds output channel
//   o = (o'>>6)*64 + (o'&3)*16 + ((o'>>2)&15)
// chosen so the GEMM epilogue can write 8B-contiguous pieces per lane.

// ---------------- out[i][o] = bias[o] (fallback path only) ------------------
__global__ void init_bias(float* __restrict__ out, const float* __restrict__ bias, int n4) {
    int i = blockIdx.x * blockDim.x + threadIdx.x;
    if (i >= n4) return;
    reinterpret_cast<float4*>(out)[i] = reinterpret_cast<const float4*>(bias)[i & 31];
}

// ---------------- fused: fp32->fp16 cvt + bias perm + Y zero row +
//                  used-cell byte-mask + remainder bucket-fill ---------------
__global__ __launch_bounds__(256) void cvt_mask(
    const float* __restrict__ x, const float* __restrict__ w,
    const float* __restrict__ bias,
    _Float16* __restrict__ Xh, _Float16* __restrict__ Wh,
    float* __restrict__ biasPerm, _Float16* __restrict__ Yz,
    const int* __restrict__ ih, const int* __restrict__ jl,
    const int* __restrict__ kc,
    unsigned char* __restrict__ maskB,
    int* __restrict__ counts, int* __restrict__ bucket,
    int* __restrict__ ovf_cnt, int* __restrict__ ovf_list,
    int Mpad, int ldY, int xv4, int xt4, int w4, int E, int eg) {
    int i = blockIdx.x * blockDim.x + threadIdx.x;
    if (i < xt4) {
        float4 v = (i < xv4) ? reinterpret_cast<const float4*>(x)[i]
                             : make_float4(0.f, 0.f, 0.f, 0.f);
        half4v h; h[0]=(_Float16)v.x; h[1]=(_Float16)v.y; h[2]=(_Float16)v.z; h[3]=(_Float16)v.w;
        reinterpret_cast<half4v*>(Xh)[i] = h;
    } else if (i < xt4 + w4) {
        int j = i - xt4;
        float4 v = reinterpret_cast<const float4*>(w)[j];
        half4v h; h[0]=(_Float16)v.x; h[1]=(_Float16)v.y; h[2]=(_Float16)v.z; h[3]=(_Float16)v.w;
        reinterpret_cast<half4v*>(Wh)[j] = h;
    } else if (i < xt4 + w4 + 32) {
        int j2 = i - xt4 - w4;           // float4 index into biasPerm (o'=4*j2)
        int wn = j2 >> 4, mrow = j2 & 15;
        float4 v;
        v.x = bias[wn * 64 + 0 * 16 + mrow];
        v.y = bias[wn * 64 + 1 * 16 + mrow];
        v.z = bias[wn * 64 + 2 * 16 + mrow];
        v.w = bias[wn * 64 + 3 * 16 + mrow];
        reinterpret_cast<float4*>(biasPerm)[j2] = v;
    } else if (i < xt4 + w4 + 48) {
        int t = i - xt4 - w4 - 32;       // Y zero row: 16 x int4 = 256 B
        reinterpret_cast<int4*>(Yz)[t] = make_int4(0, 0, 0, 0);
    } else {
        int e = i - (xt4 + w4 + 48);
        if (e < E) {
            int j = jl[e], kk = kc[e];
            maskB[(size_t)kk * Mpad + j] = 1;
            if (e >= eg) {               // remainder bucket-fill
                int ii = ih[e];
                int off = j * ldY + kk * 128;
                int pos = atomicAdd(&counts[ii], 1);
                if (pos < CAP) {
                    bucket[(size_t)ii * CAP + pos] = off;
                } else {
                    int o = atomicAdd(ovf_cnt, 1);
                    if (o < OVF_MAX) { ovf_list[2 * o] = ii; ovf_list[2 * o + 1] = off; }
                }
            }
        }
    }
}

// ---------------- GEMM: Y[m, kcell-block] = X[m,:] * W[kcell]^T -------------
// v7: LDS-transpose epilogue. Per kcell, acc is dumped into a 16 KB sE buffer
// (two passes: rows 0-63 from wm=0 waves, rows 64-127 from wm=1), then ALL
// threads re-read full rows and emit coalesced full-row NT dwordx4 stores
// (16 lanes cover one 256B Y row) -- replaces the 32x scattered-8B-per-row
// NT stores that capped the write path at ~2 TB/s in R6.
// B(kk+1) staging issued right after the post-MFMA barrier; a race-free
// vmcnt(0) sits BEFORE any of this kcell's stores are issued (outstanding =
// staging only), so the staged-B consume is properly synchronized.
// LDS 32+32+16 = 80 KB -> 2 blocks/CU. XCD-chunked bijective swizzle kept.
__global__ __launch_bounds__(256) void gemm_xw(
    const _Float16* __restrict__ Xh,   // [Mpad][128]
    const _Float16* __restrict__ Wh,   // [K][128][128]  (o-major, c contiguous)
    _Float16* __restrict__ Y,          // [Mpad][K*128]  (permuted row-blocks)
    const unsigned char* __restrict__ maskB, // used-cell bytes, idx = kcell*Mpad+m
    int Mpad, int ldY, int KD,         // KD = K/3 (y-blocks per m-tile)
    const int* __restrict__ ih, const int* __restrict__ jl,
    const int* __restrict__ kc,
    int* __restrict__ counts, int* __restrict__ bucket,
    int* __restrict__ ovf_cnt, int* __restrict__ ovf_list, int eg) {
    __shared__ ushort sA[128 * 128];   // 32 KB
    __shared__ ushort sB[128 * 128];   // 32 KB
    __shared__ ushort sE[64 * 128];    // 16 KB transpose buffer
    const int tid = threadIdx.x;

    // ---- bijective XCD-chunked swizzle (m204) -----------------------------
    const int nwg = gridDim.x;
    const int bid = blockIdx.x;
    const int q = nwg >> 3, r = nwg & 7;
    const int xcd = bid & 7, idx = bid >> 3;
    const int wg = (xcd < r) ? xcd * (q + 1) + idx
                             : r * (q + 1) + (xcd - r) * q + idx;
    const int mtile = wg / KD;
    const int ky = wg - mtile * KD;
    const int m0 = mtile * 128;
    const int kc0 = ky * 3;

    const int lane = tid & 63;
    const int wid = tid >> 6;
    const int wm = wid & 1, wn = wid >> 1;   // 2x2 wave quadrants of 64x64
    const int mrow = lane & 15;
    const int g = lane >> 4;
    const int rowloc = tid >> 2;             // epilogue: row within 64-row pass
    const int qq = tid & 3;                  // epilogue: 64B quarter of a row

    // ---- edge loads FIRST (oldest in vmcnt FIFO) --------------------------
    const bool hasE = (bid * 256) < eg;      // eg multiple of 256 -> block-uniform
    int i0 = 0, off0 = 0, pos0 = CAP;
    int ej = 0, ek = 0;
    if (hasE) {
        int e = bid * 256 + tid;
        i0 = ih[e]; ej = jl[e]; ek = kc[e];
    }
    // ---- per-row mask bytes for 3 kcells x 2 passes (6 x 1B loads) --------
    unsigned char mbq[6];
    {
        const unsigned char* mbp = maskB + m0 + rowloc;
#pragma unroll
        for (int k2 = 0; k2 < 3; ++k2) {
            mbq[k2 * 2 + 0] = mbp[(size_t)(kc0 + k2) * Mpad];
            mbq[k2 * 2 + 1] = mbp[(size_t)(kc0 + k2) * Mpad + 64];
        }
    }
    __builtin_amdgcn_sched_barrier(0);

    // ---- stage A + B(kc0): 16 global_load_lds -----------------------------
    const ushort* Ag = (const ushort*)Xh + (size_t)m0 * 128;
#pragma unroll
    for (int it = 0; it < 8; ++it) {
        int p = it * 256 + tid;
        int row = p >> 4, cpos = p & 15;
        int csrc = cpos ^ (row & 15);   // XOR swizzle keeps ds_read_b128 conflict-free
        __builtin_amdgcn_global_load_lds(
            (const __attribute__((address_space(1))) void*)(Ag + row * 128 + csrc * 8),
            (__attribute__((address_space(3))) void*)(&sA[row * 128 + cpos * 8]), 16, 0, 0);
    }
    {
        const ushort* Bg = (const ushort*)Wh + (size_t)kc0 * 128 * 128;
#pragma unroll
        for (int it = 0; it < 8; ++it) {
            int p = it * 256 + tid;
            int row = p >> 4, cpos = p & 15;
            int csrc = cpos ^ (row & 15);
            __builtin_amdgcn_global_load_lds(
                (const __attribute__((address_space(1))) void*)(Bg + row * 128 + csrc * 8),
                (__attribute__((address_space(3))) void*)(&sB[row * 128 + cpos * 8]), 16, 0, 0);
        }
    }
    __builtin_amdgcn_sched_barrier(0);

    // ---- bucket atomic (edge data already loaded; rides under kk=0 MFMA) --
    if (hasE) {
        off0 = ej * ldY + ek * 128;
        pos0 = atomicAdd(&counts[i0], 1);
        __builtin_amdgcn_sched_barrier(0);
        asm volatile("s_waitcnt vmcnt(1)" ::: "memory");   // staging+mask done; atomic in flight
    } else {
        __builtin_amdgcn_sched_barrier(0);
        asm volatile("s_waitcnt vmcnt(0)" ::: "memory");
    }
    __builtin_amdgcn_sched_barrier(0);
    __builtin_amdgcn_s_barrier();
    __builtin_amdgcn_sched_barrier(0);

    for (int kk = 0; kk < 3; ++kk) {
        f32x4 acc[4][4] = {};
#pragma unroll
        for (int kb = 0; kb < 4; ++kb) {
            half8 af[4], bf[4];
#pragma unroll
            for (int t = 0; t < 4; ++t) {
                int cpos8 = ((kb * 4 + g) ^ mrow) * 8;
                int ra = wm * 64 + t * 16 + mrow;
                af[t] = *reinterpret_cast<const half8*>(&sA[ra * 128 + cpos8]);
                int rb = wn * 64 + t * 16 + mrow;
                bf[t] = *reinterpret_cast<const half8*>(&sB[rb * 128 + cpos8]);
            }
#pragma unroll
            for (int mt = 0; mt < 4; ++mt)
#pragma unroll
                for (int nt = 0; nt < 4; ++nt)
                    acc[mt][nt] = __builtin_amdgcn_mfma_f32_16x16x32_f16(
                        af[mt], bf[nt], acc[mt][nt], 0, 0, 0);
        }
        __builtin_amdgcn_s_barrier();            // all waves done reading sB(kk)
        __builtin_amdgcn_sched_barrier(0);
        if (kk < 2) {                            // stage B(kk+1); synced at vmcnt(0) below
            const ushort* Bg = (const ushort*)Wh + (size_t)(kc0 + kk + 1) * 128 * 128;
#pragma unroll
            for (int it = 0; it < 8; ++it) {
                int p = it * 256 + tid;
                int row = p >> 4, cpos = p & 15;
                int csrc = cpos ^ (row & 15);
                __builtin_amdgcn_global_load_lds(
                    (const __attribute__((address_space(1))) void*)(Bg + row * 128 + csrc * 8),
                    (__attribute__((address_space(3))) void*)(&sB[row * 128 + cpos * 8]), 16, 0, 0);
            }
        }
        __builtin_amdgcn_sched_barrier(0);
        if (kk == 0 && hasE) {                   // consume atomic (compiler-counted wait)
            if (pos0 < CAP) {
                bucket[(size_t)i0 * CAP + pos0] = off0;
            } else {
                int o = atomicAdd(ovf_cnt, 1);
                if (o < OVF_MAX) { ovf_list[2 * o] = i0; ovf_list[2 * o + 1] = off0; }
            }
        }

        // ---- two-pass LDS-transpose epilogue ------------------------------
#pragma unroll
        for (int pass = 0; pass < 2; ++pass) {
            if (wm == pass) {                    // this wave's rows into sE
                char* se = (char*)sE;
#pragma unroll
                for (int mt = 0; mt < 4; ++mt)
#pragma unroll
                    for (int rr = 0; rr < 4; ++rr) {
                        int rl = mt * 16 + g * 4 + rr;
                        int c = wn * 8 + (mrow >> 1);
                        int addr = rl * 256 + ((c ^ (rl & 15)) * 16) + (mrow & 1) * 8;
                        half4v hv;
#pragma unroll
                        for (int nt = 0; nt < 4; ++nt) hv[nt] = (_Float16)acc[mt][nt][rr];
                        *reinterpret_cast<half4v*>(se + addr) = hv;
                    }
            }
            asm volatile("s_waitcnt lgkmcnt(0)" ::: "memory");
            __builtin_amdgcn_s_barrier();        // sE visible to all
            __builtin_amdgcn_sched_barrier(0);
            if (pass == 0 && kk < 2) {
                // staged B(kk+1) complete before any of this kcell's stores
                // are issued (outstanding = 8 staging [+bucket]); race-free.
                asm volatile("s_waitcnt vmcnt(0)" ::: "memory");
                __builtin_amdgcn_sched_barrier(0);
            }
            if (mbq[kk * 2 + pass]) {            // row used -> coalesced NT stores
                const char* se = (const char*)sE;
                int grow = pass * 64 + rowloc;
                _Float16* Yt = Y + (size_t)(m0 + grow) * ldY + (kc0 + kk) * 128 + qq * 32;
#pragma unroll
                for (int j = 0; j < 4; ++j) {
                    int pc = (qq * 4 + j) ^ (rowloc & 15);
                    i32x4 v = *reinterpret_cast<const i32x4*>(se + rowloc * 256 + pc * 16);
                    __builtin_nontemporal_store(v, reinterpret_cast<i32x4*>(Yt + j * 8));
                }
            }
            __builtin_amdgcn_s_barrier();        // sE reads done -> reusable
            __builtin_amdgcn_sched_barrier(0);
        }
        // trailing barrier doubles as pre-MFMA sync for next kcell
    }
}

// ---------------- gather: out[i] = bias + sum_{e in bucket[i]} Y[off_e] -----
// 4 points per wave, 16 lanes x half8 per row; unroll-8 for loads in flight
// (padding rounds hit the L1-cached zero row -> nearly free).
__global__ __launch_bounds__(256) void gather_out(
    const _Float16* __restrict__ Y, const int* __restrict__ counts,
    const int* __restrict__ bucket, const float* __restrict__ biasPerm,
    float* __restrict__ out, int Nhigh, int zoff) {
    int wave = (blockIdx.x * blockDim.x + threadIdx.x) >> 6;
    int lane = threadIdx.x & 63;
    int p = lane >> 4;                  // point within wave
    int sub = lane & 15;                // 16B piece within row
    int i = wave * 4 + p;
    bool act = i < Nhigh;
    int iC = act ? i : 0;
    int nb = counts[iC];
    if (nb > CAP) nb = CAP;
    const int* bk = bucket + (size_t)iC * CAP;
    int offsA = bk[sub];                // slots 0..15 across the quarter
    int offsB = bk[sub + 16];           // slots 16..31
    float4 b0 = reinterpret_cast<const float4*>(biasPerm)[sub * 2];
    float4 b1 = reinterpret_cast<const float4*>(biasPerm)[sub * 2 + 1];
    float acc[8] = {b0.x, b0.y, b0.z, b0.w, b1.x, b1.y, b1.z, b1.w};

    int nmax = nb;
    nmax = max(nmax, __shfl_xor(nmax, 16));
    nmax = max(nmax, __shfl_xor(nmax, 32));

    for (int e0 = 0; e0 < nmax; e0 += 8) {
#pragma unroll
        for (int u = 0; u < 8; ++u) {
            int e = e0 + u;                           // wave-uniform
            int off = (e < 16) ? __shfl(offsA, p * 16 + (e & 15))
                               : __shfl(offsB, p * 16 + (e & 15));
            bool valid = act && (e < nb);
            off = valid ? off : zoff;                 // zero row
            half8 h = *reinterpret_cast<const half8*>(Y + (size_t)off + sub * 8);
#pragma unroll
            for (int t = 0; t < 8; ++t) acc[t] += (float)h[t];
        }
    }
    if (act) {
        // channels o = obase+16b and o+1 are t=b and t=b+4 -> 8B stores
        float* op = out + (size_t)i * 128;
        int obase = (sub >> 3) * 64 + (sub & 7) * 2;
#pragma unroll
        for (int b = 0; b < 4; ++b) {
            f32x2 v; v[0] = acc[b]; v[1] = acc[b + 4];
            __builtin_nontemporal_store(
                v, reinterpret_cast<f32x2*>(op + obase + 16 * b));
        }
    }
}

// ---------------- rare overflow application (normally 0 entries) ------------
__global__ void apply_overflow(const int* __restrict__ ovf_cnt, const int* __restrict__ ovf_list,
                               const _Float16* __restrict__ Y, float* __restrict__ out) {
    int n = *ovf_cnt;
    if (n > OVF_MAX) n = OVF_MAX;
    int lane = threadIdx.x & 63;
    int w = threadIdx.x >> 6;        // 4 waves, 1 block
    int o0p = 2 * lane, o1p = 2 * lane + 1;
    int o0 = (o0p >> 6) * 64 + (o0p & 3) * 16 + ((o0p >> 2) & 15);
    int o1 = (o1p >> 6) * 64 + (o1p & 3) * 16 + ((o1p >> 2) & 15);
    for (int o = w; o < n; o += 4) {
        int i = ovf_list[2 * o], off = ovf_list[2 * o + 1];
        half2v h = *reinterpret_cast<const half2v*>(Y + (size_t)off + lane * 2);
        float* dst = out + (size_t)i * 128;
        unsafeAtomicAdd(dst + o0, (float)h[0]);
        unsafeAtomicAdd(dst + o1, (float)h[1]);
    }
}

// ---------------- tier-3 fallback: direct per-edge matvec -------------------
__global__ void fallback_edge(const float* __restrict__ x, const float* __restrict__ w,
                              const int* __restrict__ ih, const int* __restrict__ jl,
                              const int* __restrict__ kc, float* __restrict__ out, int E) {
    int e = blockIdx.x;
    if (e >= E) return;
    int lane = threadIdx.x;   // 64 threads
    int i = ih[e], j = jl[e], k = kc[e];
    const float* xr = x + (size_t)j * 128;
    const float* wk = w + (size_t)k * 128 * 128;
    float s0 = 0.f, s1 = 0.f;
    for (int c = 0; c < 128; ++c) {
        float xv = xr[c];
        s0 += wk[(size_t)lane * 128 + c] * xv;
        s1 += wk[(size_t)(lane + 64) * 128 + c] * xv;
    }
    unsafeAtomicAdd(&out[(size_t)i * 128 + lane], s0);
    unsafeAtomicAdd(&out[(size_t)i * 128 + 64 + lane], s1);
}

extern "C" void kernel_launch(void* const* d_in, const int* in_sizes, int n_in,
                              void* d_out, int out_size, void* d_ws, size_t ws_size,
                              hipStream_t stream) {
    const float* x    = (const float*)d_in[0];
    const float* w    = (const float*)d_in[1];
    const float* bias = (const float*)d_in[2];
    const int*   ih   = (const int*)d_in[3];
    const int*   jl   = (const int*)d_in[4];
    const int*   kc   = (const int*)d_in[5];
    float* out = (float*)d_out;

    const int C = 128;
    const int Nlow = in_sizes[0] / C;
    const int K = in_sizes[1] / (C * C);
    const int E = in_sizes[3];
    const int ldY = K * C;
    const int Nhigh = out_size / C;

    const int mtiles = (Nlow + 127) / 128;
    const int Mpad = mtiles * 128;

    // ---- workspace layout -------------------------------------------------
    size_t off = 0;
    auto alloc = [&](size_t bytes) { size_t o = off; off = (off + bytes + 255) & ~(size_t)255; return o; };
    size_t xh_off   = alloc((size_t)Mpad * C * 2);
    size_t wh_off   = alloc((size_t)K * C * C * 2);
    size_t bp_off   = alloc((size_t)C * 4);                  // permuted bias
    size_t cnt_off  = alloc(((size_t)Nhigh + 1) * 4 + (size_t)Mpad * K); // counts+ovf+byte mask
    size_t ovl_off  = alloc((size_t)OVF_MAX * 2 * 4);
    size_t bkt_off  = alloc((size_t)Nhigh * CAP * 4);
    size_t y_off    = alloc(((size_t)Mpad * ldY + C) * 2);   // + zero row
    size_t need_sort = off;

    _Float16* Xh = (_Float16*)((char*)d_ws + xh_off);
    _Float16* Wh = (_Float16*)((char*)d_ws + wh_off);
    float* biasPerm = (float*)((char*)d_ws + bp_off);
    int* counts  = (int*)((char*)d_ws + cnt_off);
    int* ovf_cnt = counts + Nhigh;
    unsigned char* maskB = (unsigned char*)(counts + Nhigh + 1);
    int* ovf_lst = (int*)((char*)d_ws + ovl_off);
    int* bucket  = (int*)((char*)d_ws + bkt_off);
    _Float16* Y  = (_Float16*)((char*)d_ws + y_off);
    const int zoff = Mpad * ldY;                             // zero-row offset (halfwords)

    if (ws_size >= need_sort && (K % 3) == 0) {
        int xv4 = Nlow * C / 4, xt4 = Mpad * C / 4;
        int w4 = K * C * C / 4;
        int KD = K / 3;
        int nwg = mtiles * KD;
        long long cap256 = (long long)nwg * 256;
        int eg = (E < cap256) ? (E & ~255) : (int)cap256;   // gemm-handled edges [0,eg)

        // counts + ovf + byte mask are contiguous -> one async memset
        size_t nzb = ((size_t)Nhigh + 1) * 4 + (size_t)Mpad * K;
        hipMemsetAsync(counts, 0, nzb, stream);

        int totalCvt = xt4 + w4 + 48 + E;
        cvt_mask<<<(totalCvt + 255) / 256, 256, 0, stream>>>(
            x, w, bias, Xh, Wh, biasPerm, Y + (size_t)zoff,
            ih, jl, kc, maskB, counts, bucket, ovf_cnt, ovf_lst,
            Mpad, ldY, xv4, xt4, w4, E, eg);

        gemm_xw<<<nwg, 256, 0, stream>>>(
            Xh, Wh, Y, maskB, Mpad, ldY, KD,
            ih, jl, kc, counts, bucket, ovf_cnt, ovf_lst, eg);

        gather_out<<<(Nhigh + 15) / 16, 256, 0, stream>>>(
            Y, counts, bucket, biasPerm, out, Nhigh, zoff);
        apply_overflow<<<1, 256, 0, stream>>>(ovf_cnt, ovf_lst, Y, out);
    } else {
        int n4out = out_size / 4;
        init_bias<<<(n4out + 255) / 256, 256, 0, stream>>>(out, bias, n4out);
        fallback_edge<<<E, 64, 0, stream>>>(x, w, ih, jl, kc, out, E);
    }
}

// Round 8
// 328.669 us; speedup vs baseline: 1.0167x; 1.0167x over previous
//
#include <hip/hip_runtime.h>

typedef _Float16 half8 __attribute__((ext_vector_type(8)));
typedef _Float16 half4v __attribute__((ext_vector_type(4)));
typedef _Float16 half2v __attribute__((ext_vector_type(2)));
typedef float f32x4 __attribute__((ext_vector_type(4)));
typedef float f32x2 __attribute__((ext_vector_type(2)));

#define CAP 32          // bucket capacity per output point (mean load = 5)
#define OVF_MAX 4096

// Y layout (R8): [K][Mpad][128] -- one block's kcell writes 128 consecutive
// 256B rows = dense 32KB streaming region (HBM page locality for the write
// path, which R6/R7 showed pinned at ~2 TB/s under the strided layout).
// Row-internal permutation unchanged: position o' holds output channel
//   o = (o'>>6)*64 + (o'&3)*16 + ((o'>>2)&15)

// ---------------- out[i][o] = bias[o] (fallback path only) ------------------
__global__ void init_bias(float* __restrict__ out, const float* __restrict__ bias, int n4) {
    int i = blockIdx.x * blockDim.x + threadIdx.x;
    if (i >= n4) return;
    reinterpret_cast<float4*>(out)[i] = reinterpret_cast<const float4*>(bias)[i & 31];
}

// ---------------- fused: fp32->fp16 cvt + bias perm + Y zero row +
//                  used-cell byte-mask + remainder bucket-fill ---------------
__global__ __launch_bounds__(256) void cvt_mask(
    const float* __restrict__ x, const float* __restrict__ w,
    const float* __restrict__ bias,
    _Float16* __restrict__ Xh, _Float16* __restrict__ Wh,
    float* __restrict__ biasPerm, _Float16* __restrict__ Yz,
    const int* __restrict__ ih, const int* __restrict__ jl,
    const int* __restrict__ kc,
    unsigned char* __restrict__ maskB,
    int* __restrict__ counts, int* __restrict__ bucket,
    int* __restrict__ ovf_cnt, int* __restrict__ ovf_list,
    int Mpad, int xv4, int xt4, int w4, int E, int eg) {
    int i = blockIdx.x * blockDim.x + threadIdx.x;
    if (i < xt4) {
        float4 v = (i < xv4) ? reinterpret_cast<const float4*>(x)[i]
                             : make_float4(0.f, 0.f, 0.f, 0.f);
        half4v h; h[0]=(_Float16)v.x; h[1]=(_Float16)v.y; h[2]=(_Float16)v.z; h[3]=(_Float16)v.w;
        reinterpret_cast<half4v*>(Xh)[i] = h;
    } else if (i < xt4 + w4) {
        int j = i - xt4;
        float4 v = reinterpret_cast<const float4*>(w)[j];
        half4v h; h[0]=(_Float16)v.x; h[1]=(_Float16)v.y; h[2]=(_Float16)v.z; h[3]=(_Float16)v.w;
        reinterpret_cast<half4v*>(Wh)[j] = h;
    } else if (i < xt4 + w4 + 32) {
        int j2 = i - xt4 - w4;           // float4 index into biasPerm (o'=4*j2)
        int wn = j2 >> 4, mrow = j2 & 15;
        float4 v;
        v.x = bias[wn * 64 + 0 * 16 + mrow];
        v.y = bias[wn * 64 + 1 * 16 + mrow];
        v.z = bias[wn * 64 + 2 * 16 + mrow];
        v.w = bias[wn * 64 + 3 * 16 + mrow];
        reinterpret_cast<float4*>(biasPerm)[j2] = v;
    } else if (i < xt4 + w4 + 48) {
        int t = i - xt4 - w4 - 32;       // Y zero row: 16 x int4 = 256 B
        reinterpret_cast<int4*>(Yz)[t] = make_int4(0, 0, 0, 0);
    } else {
        int e = i - (xt4 + w4 + 48);
        if (e < E) {
            int j = jl[e], kk = kc[e];
            maskB[(size_t)kk * Mpad + j] = 1;
            if (e >= eg) {               // remainder bucket-fill
                int ii = ih[e];
                int off = (kk * Mpad + j) * 128;   // [K][Mpad][128] row offset
                int pos = atomicAdd(&counts[ii], 1);
                if (pos < CAP) {
                    bucket[(size_t)ii * CAP + pos] = off;
                } else {
                    int o = atomicAdd(ovf_cnt, 1);
                    if (o < OVF_MAX) { ovf_list[2 * o] = ii; ovf_list[2 * o + 1] = off; }
                }
            }
        }
    }
}

// ---------------- GEMM: Y[kcell][m] = X[m,:] * W[kcell]^T -------------------
// R6-verified schedule (113 us): A+B staged via global_load_lds, counted
// vmcnt waits (never 0 mid-loop), raw barriers, bucket atomic hidden in the
// prologue, masked branchy NT epilogue, XCD-chunked bijective swizzle.
// R8 change: Y layout [K][Mpad][128] -> per-kcell stores are a dense 32KB
// region (rows at 256B stride; each wave store-quad = 128B contiguous).
__global__ __launch_bounds__(256) void gemm_xw(
    const _Float16* __restrict__ Xh,   // [Mpad][128]
    const _Float16* __restrict__ Wh,   // [K][128][128]  (o-major, c contiguous)
    _Float16* __restrict__ Y,          // [K][Mpad][128] (permuted rows)
    const unsigned char* __restrict__ maskB, // used-cell bytes, idx = kcell*Mpad+m
    int Mpad, int KD,                  // KD = K/3 (y-blocks per m-tile)
    const int* __restrict__ ih, const int* __restrict__ jl,
    const int* __restrict__ kc,
    int* __restrict__ counts, int* __restrict__ bucket,
    int* __restrict__ ovf_cnt, int* __restrict__ ovf_list, int eg) {
    __shared__ ushort sA[128 * 128];
    __shared__ ushort sB[128 * 128];
    const int tid = threadIdx.x;

    // ---- bijective XCD-chunked swizzle (m204) -----------------------------
    const int nwg = gridDim.x;
    const int bid = blockIdx.x;
    const int q = nwg >> 3, r = nwg & 7;
    const int xcd = bid & 7, idx = bid >> 3;
    const int wg = (xcd < r) ? xcd * (q + 1) + idx
                             : r * (q + 1) + (xcd - r) * q + idx;
    const int mtile = wg / KD;
    const int ky = wg - mtile * KD;
    const int m0 = mtile * 128;
    const int kc0 = ky * 3;

    const ushort* Ag = (const ushort*)Xh + (size_t)m0 * 128;
#pragma unroll
    for (int it = 0; it < 8; ++it) {
        int p = it * 256 + tid;
        int row = p >> 4, cpos = p & 15;
        int csrc = cpos ^ (row & 15);   // XOR swizzle keeps ds_read_b128 conflict-free
        __builtin_amdgcn_global_load_lds(
            (const __attribute__((address_space(1))) void*)(Ag + row * 128 + csrc * 8),
            (__attribute__((address_space(3))) void*)(&sA[row * 128 + cpos * 8]), 16, 0, 0);
    }
    {   // stage B for kcell kc0
        const ushort* Bg = (const ushort*)Wh + (size_t)kc0 * 128 * 128;
#pragma unroll
        for (int it = 0; it < 8; ++it) {
            int p = it * 256 + tid;
            int row = p >> 4, cpos = p & 15;
            int csrc = cpos ^ (row & 15);
            __builtin_amdgcn_global_load_lds(
                (const __attribute__((address_space(1))) void*)(Bg + row * 128 + csrc * 8),
                (__attribute__((address_space(3))) void*)(&sB[row * 128 + cpos * 8]), 16, 0, 0);
        }
    }
    __builtin_amdgcn_sched_barrier(0);   // pin: all 16 staging ops issued above

    // ---- bucket-fill issue: 3 loads + 1 atomic per thread (uniform) -------
    const bool hasE = (bid * 256) < eg;  // eg multiple of 256 -> block-uniform
    int i0 = 0, off0 = 0, pos0 = CAP;
    if (hasE) {
        int e = bid * 256 + tid;
        i0 = ih[e];
        off0 = (kc[e] * Mpad + jl[e]) * 128;
        pos0 = atomicAdd(&counts[i0], 1);
        __builtin_amdgcn_sched_barrier(0);
        asm volatile("s_waitcnt vmcnt(4)" ::: "memory");   // staging done; atomic in flight
    } else {
        __builtin_amdgcn_sched_barrier(0);
        asm volatile("s_waitcnt vmcnt(0)" ::: "memory");
    }
    __builtin_amdgcn_sched_barrier(0);
    __builtin_amdgcn_s_barrier();        // raw: no vmcnt(0) drain of the atomic
    __builtin_amdgcn_sched_barrier(0);

    const int lane = tid & 63;
    const int wid = tid >> 6;
    const int wm = wid & 1, wn = wid >> 1;   // 2x2 wave quadrants of 64x64
    const int mrow = lane & 15;
    const int g = lane >> 4;

    for (int kk = 0; kk < 3; ++kk) {
        f32x4 acc[4][4] = {};
#pragma unroll
        for (int kb = 0; kb < 4; ++kb) {
            half8 af[4], bf[4];
#pragma unroll
            for (int t = 0; t < 4; ++t) {
                int cpos8 = ((kb * 4 + g) ^ mrow) * 8;
                int ra = wm * 64 + t * 16 + mrow;
                af[t] = *reinterpret_cast<const half8*>(&sA[ra * 128 + cpos8]);
                int rb = wn * 64 + t * 16 + mrow;
                bf[t] = *reinterpret_cast<const half8*>(&sB[rb * 128 + cpos8]);
            }
#pragma unroll
            for (int mt = 0; mt < 4; ++mt)
#pragma unroll
                for (int nt = 0; nt < 4; ++nt)
                    acc[mt][nt] = __builtin_amdgcn_mfma_f32_16x16x32_f16(
                        af[mt], bf[nt], acc[mt][nt], 0, 0, 0);
        }
        if (kk < 2) {
            // raw barrier: compiler's lgkmcnt waits before the MFMAs above
            // guarantee every wave's sB ds_reads retired; no vmcnt drain needed.
            __builtin_amdgcn_s_barrier();
            __builtin_amdgcn_sched_barrier(0);
            const ushort* Bg = (const ushort*)Wh + (size_t)(kc0 + kk + 1) * 128 * 128;
#pragma unroll
            for (int it = 0; it < 8; ++it) {     // 8 staging loads (oldest)
                int p = it * 256 + tid;
                int row = p >> 4, cpos = p & 15;
                int csrc = cpos ^ (row & 15);
                __builtin_amdgcn_global_load_lds(
                    (const __attribute__((address_space(1))) void*)(Bg + row * 128 + csrc * 8),
                    (__attribute__((address_space(3))) void*)(&sB[row * 128 + cpos * 8]), 16, 0, 0);
            }
            __builtin_amdgcn_sched_barrier(0);
        }
        if (kk == 0 && hasE) {                   // consume atomic result
            if (pos0 < CAP) {
                bucket[(size_t)i0 * CAP + pos0] = off0;
            } else {
                int o = atomicAdd(ovf_cnt, 1);
                if (o < OVF_MAX) { ovf_list[2 * o] = i0; ovf_list[2 * o + 1] = off0; }
            }
        }
        // ---- epilogue: masked 8B NT stores into the dense [K][Mpad][128]
        // plane: per (mt,r), 16 consecutive lanes write 128B contiguous ----
        const unsigned char* mBp = maskB + (size_t)(kc0 + kk) * Mpad + m0 + wm * 64;
        _Float16* Yt = Y + ((size_t)(kc0 + kk) * Mpad + m0) * 128 + wn * 64 + mrow * 4;
#pragma unroll
        for (int mt = 0; mt < 4; ++mt) {
            unsigned mw = *reinterpret_cast<const unsigned*>(mBp + mt * 16 + g * 4);
            if (mw) {
#pragma unroll
                for (int r = 0; r < 4; ++r) {
                    if ((mw >> (8 * r)) & 0xFFu) {
                        int row = wm * 64 + mt * 16 + g * 4 + r;
                        half4v hv;
#pragma unroll
                        for (int nt = 0; nt < 4; ++nt) hv[nt] = (_Float16)acc[mt][nt][r];
                        __builtin_nontemporal_store(
                            hv, reinterpret_cast<half4v*>(Yt + (size_t)row * 128));
                    }
                }
            }
        }
        __builtin_amdgcn_sched_barrier(0);
        if (kk == 0) {
            if (hasE) { asm volatile("s_waitcnt vmcnt(17)" ::: "memory"); }
            else      { asm volatile("s_waitcnt vmcnt(16)" ::: "memory"); }
            __builtin_amdgcn_sched_barrier(0);
            __builtin_amdgcn_s_barrier();
            __builtin_amdgcn_sched_barrier(0);
        } else if (kk == 1) {
            asm volatile("s_waitcnt vmcnt(16)" ::: "memory");
            __builtin_amdgcn_sched_barrier(0);
            __builtin_amdgcn_s_barrier();
            __builtin_amdgcn_sched_barrier(0);
        }
        // kk==2: fall through; endpgm drains outstanding stores
    }
}

// ---------------- gather: out[i] = bias + sum_{e in bucket[i]} Y[off_e] -----
// 4 points per wave, 16 lanes x half8 per row; unroll-8 for loads in flight
// (padding rounds hit the L1-cached zero row -> nearly free).
__global__ __launch_bounds__(256) void gather_out(
    const _Float16* __restrict__ Y, const int* __restrict__ counts,
    const int* __restrict__ bucket, const float* __restrict__ biasPerm,
    float* __restrict__ out, int Nhigh, int zoff) {
    int wave = (blockIdx.x * blockDim.x + threadIdx.x) >> 6;
    int lane = threadIdx.x & 63;
    int p = lane >> 4;                  // point within wave
    int sub = lane & 15;                // 16B piece within row
    int i = wave * 4 + p;
    bool act = i < Nhigh;
    int iC = act ? i : 0;
    int nb = counts[iC];
    if (nb > CAP) nb = CAP;
    const int* bk = bucket + (size_t)iC * CAP;
    int offsA = bk[sub];                // slots 0..15 across the quarter
    int offsB = bk[sub + 16];           // slots 16..31
    float4 b0 = reinterpret_cast<const float4*>(biasPerm)[sub * 2];
    float4 b1 = reinterpret_cast<const float4*>(biasPerm)[sub * 2 + 1];
    float acc[8] = {b0.x, b0.y, b0.z, b0.w, b1.x, b1.y, b1.z, b1.w};

    int nmax = nb;
    nmax = max(nmax, __shfl_xor(nmax, 16));
    nmax = max(nmax, __shfl_xor(nmax, 32));

    for (int e0 = 0; e0 < nmax; e0 += 8) {
#pragma unroll
        for (int u = 0; u < 8; ++u) {
            int e = e0 + u;                           // wave-uniform
            int off = (e < 16) ? __shfl(offsA, p * 16 + (e & 15))
                               : __shfl(offsB, p * 16 + (e & 15));
            bool valid = act && (e < nb);
            off = valid ? off : zoff;                 // zero row
            half8 h = *reinterpret_cast<const half8*>(Y + (size_t)off + sub * 8);
#pragma unroll
            for (int t = 0; t < 8; ++t) acc[t] += (float)h[t];
        }
    }
    if (act) {
        // channels o = obase+16b and o+1 are t=b and t=b+4 -> 8B stores
        float* op = out + (size_t)i * 128;
        int obase = (sub >> 3) * 64 + (sub & 7) * 2;
#pragma unroll
        for (int b = 0; b < 4; ++b) {
            f32x2 v; v[0] = acc[b]; v[1] = acc[b + 4];
            __builtin_nontemporal_store(
                v, reinterpret_cast<f32x2*>(op + obase + 16 * b));
        }
    }
}

// ---------------- rare overflow application (normally 0 entries) ------------
__global__ void apply_overflow(const int* __restrict__ ovf_cnt, const int* __restrict__ ovf_list,
                               const _Float16* __restrict__ Y, float* __restrict__ out) {
    int n = *ovf_cnt;
    if (n > OVF_MAX) n = OVF_MAX;
    int lane = threadIdx.x & 63;
    int w = threadIdx.x >> 6;        // 4 waves, 1 block
    int o0p = 2 * lane, o1p = 2 * lane + 1;
    int o0 = (o0p >> 6) * 64 + (o0p & 3) * 16 + ((o0p >> 2) & 15);
    int o1 = (o1p >> 6) * 64 + (o1p & 3) * 16 + ((o1p >> 2) & 15);
    for (int o = w; o < n; o += 4) {
        int i = ovf_list[2 * o], off = ovf_list[2 * o + 1];
        half2v h = *reinterpret_cast<const half2v*>(Y + (size_t)off + lane * 2);
        float* dst = out + (size_t)i * 128;
        unsafeAtomicAdd(dst + o0, (float)h[0]);
        unsafeAtomicAdd(dst + o1, (float)h[1]);
    }
}

// ---------------- tier-3 fallback: direct per-edge matvec -------------------
__global__ void fallback_edge(const float* __restrict__ x, const float* __restrict__ w,
                              const int* __restrict__ ih, const int* __restrict__ jl,
                              const int* __restrict__ kc, float* __restrict__ out, int E) {
    int e = blockIdx.x;
    if (e >= E) return;
    int lane = threadIdx.x;   // 64 threads
    int i = ih[e], j = jl[e], k = kc[e];
    const float* xr = x + (size_t)j * 128;
    const float* wk = w + (size_t)k * 128 * 128;
    float s0 = 0.f, s1 = 0.f;
    for (int c = 0; c < 128; ++c) {
        float xv = xr[c];
        s0 += wk[(size_t)lane * 128 + c] * xv;
        s1 += wk[(size_t)(lane + 64) * 128 + c] * xv;
    }
    unsafeAtomicAdd(&out[(size_t)i * 128 + lane], s0);
    unsafeAtomicAdd(&out[(size_t)i * 128 + 64 + lane], s1);
}

extern "C" void kernel_launch(void* const* d_in, const int* in_sizes, int n_in,
                              void* d_out, int out_size, void* d_ws, size_t ws_size,
                              hipStream_t stream) {
    const float* x    = (const float*)d_in[0];
    const float* w    = (const float*)d_in[1];
    const float* bias = (const float*)d_in[2];
    const int*   ih   = (const int*)d_in[3];
    const int*   jl   = (const int*)d_in[4];
    const int*   kc   = (const int*)d_in[5];
    float* out = (float*)d_out;

    const int C = 128;
    const int Nlow = in_sizes[0] / C;
    const int K = in_sizes[1] / (C * C);
    const int E = in_sizes[3];
    const int Nhigh = out_size / C;

    const int mtiles = (Nlow + 127) / 128;
    const int Mpad = mtiles * 128;

    // ---- workspace layout -------------------------------------------------
    size_t off = 0;
    auto alloc = [&](size_t bytes) { size_t o = off; off = (off + bytes + 255) & ~(size_t)255; return o; };
    size_t xh_off   = alloc((size_t)Mpad * C * 2);
    size_t wh_off   = alloc((size_t)K * C * C * 2);
    size_t bp_off   = alloc((size_t)C * 4);                  // permuted bias
    size_t cnt_off  = alloc(((size_t)Nhigh + 1) * 4 + (size_t)Mpad * K); // counts+ovf+byte mask
    size_t ovl_off  = alloc((size_t)OVF_MAX * 2 * 4);
    size_t bkt_off  = alloc((size_t)Nhigh * CAP * 4);
    size_t y_off    = alloc(((size_t)K * Mpad * C + C) * 2); // [K][Mpad][128] + zero row
    size_t need_sort = off;

    _Float16* Xh = (_Float16*)((char*)d_ws + xh_off);
    _Float16* Wh = (_Float16*)((char*)d_ws + wh_off);
    float* biasPerm = (float*)((char*)d_ws + bp_off);
    int* counts  = (int*)((char*)d_ws + cnt_off);
    int* ovf_cnt = counts + Nhigh;
    unsigned char* maskB = (unsigned char*)(counts + Nhigh + 1);
    int* ovf_lst = (int*)((char*)d_ws + ovl_off);
    int* bucket  = (int*)((char*)d_ws + bkt_off);
    _Float16* Y  = (_Float16*)((char*)d_ws + y_off);
    const int zoff = K * Mpad * C;                           // zero-row offset (halfwords)

    if (ws_size >= need_sort && (K % 3) == 0) {
        int xv4 = Nlow * C / 4, xt4 = Mpad * C / 4;
        int w4 = K * C * C / 4;
        int KD = K / 3;
        int nwg = mtiles * KD;
        long long cap256 = (long long)nwg * 256;
        int eg = (E < cap256) ? (E & ~255) : (int)cap256;   // gemm-handled edges [0,eg)

        // counts + ovf + byte mask are contiguous -> one async memset
        size_t nzb = ((size_t)Nhigh + 1) * 4 + (size_t)Mpad * K;
        hipMemsetAsync(counts, 0, nzb, stream);

        int totalCvt = xt4 + w4 + 48 + E;
        cvt_mask<<<(totalCvt + 255) / 256, 256, 0, stream>>>(
            x, w, bias, Xh, Wh, biasPerm, Y + (size_t)zoff,
            ih, jl, kc, maskB, counts, bucket, ovf_cnt, ovf_lst,
            Mpad, xv4, xt4, w4, E, eg);

        gemm_xw<<<nwg, 256, 0, stream>>>(
            Xh, Wh, Y, maskB, Mpad, KD,
            ih, jl, kc, counts, bucket, ovf_cnt, ovf_lst, eg);

        gather_out<<<(Nhigh + 15) / 16, 256, 0, stream>>>(
            Y, counts, bucket, biasPerm, out, Nhigh, zoff);
        apply_overflow<<<1, 256, 0, stream>>>(ovf_cnt, ovf_lst, Y, out);
    } else {
        int n4out = out_size / 4;
        init_bias<<<(n4out + 255) / 256, 256, 0, stream>>>(out, bias, n4out);
        fallback_edge<<<E, 64, 0, stream>>>(x, w, ih, jl, kc, out, E);
    }
}

// Round 9
// 323.302 us; speedup vs baseline: 1.0336x; 1.0166x over previous
//
#include <hip/hip_runtime.h>

typedef _Float16 half8 __attribute__((ext_vector_type(8)));
typedef _Float16 half4v __attribute__((ext_vector_type(4)));
typedef _Float16 half2v __attribute__((ext_vector_type(2)));
typedef float f32x4 __attribute__((ext_vector_type(4)));
typedef float f32x2 __attribute__((ext_vector_type(2)));

#define CAP 32          // bucket capacity per output point (mean load = 5)
#define OVF_MAX 4096

// Y layout: [K][Mpad][128] (dense per-kcell planes). Row-internal permutation:
// position o' holds output channel o = (o'>>6)*64 + (o'&3)*16 + ((o'>>2)&15)

// ---------------- out[i][o] = bias[o] (fallback path only) ------------------
__global__ void init_bias(float* __restrict__ out, const float* __restrict__ bias, int n4) {
    int i = blockIdx.x * blockDim.x + threadIdx.x;
    if (i >= n4) return;
    reinterpret_cast<float4*>(out)[i] = reinterpret_cast<const float4*>(bias)[i & 31];
}

// ---------------- fused: fp32->fp16 cvt + bias perm + Y zero row +
//                  used-cell byte-mask + remainder bucket-fill ---------------
__global__ __launch_bounds__(256) void cvt_mask(
    const float* __restrict__ x, const float* __restrict__ w,
    const float* __restrict__ bias,
    _Float16* __restrict__ Xh, _Float16* __restrict__ Wh,
    float* __restrict__ biasPerm, _Float16* __restrict__ Yz,
    const int* __restrict__ ih, const int* __restrict__ jl,
    const int* __restrict__ kc,
    unsigned char* __restrict__ maskB,
    int* __restrict__ counts, int* __restrict__ bucket,
    int* __restrict__ ovf_cnt, int* __restrict__ ovf_list,
    int Mpad, int xv4, int xt4, int w4, int E, int eg) {
    int i = blockIdx.x * blockDim.x + threadIdx.x;
    if (i < xt4) {
        float4 v = (i < xv4) ? reinterpret_cast<const float4*>(x)[i]
                             : make_float4(0.f, 0.f, 0.f, 0.f);
        half4v h; h[0]=(_Float16)v.x; h[1]=(_Float16)v.y; h[2]=(_Float16)v.z; h[3]=(_Float16)v.w;
        reinterpret_cast<half4v*>(Xh)[i] = h;
    } else if (i < xt4 + w4) {
        int j = i - xt4;
        float4 v = reinterpret_cast<const float4*>(w)[j];
        half4v h; h[0]=(_Float16)v.x; h[1]=(_Float16)v.y; h[2]=(_Float16)v.z; h[3]=(_Float16)v.w;
        reinterpret_cast<half4v*>(Wh)[j] = h;
    } else if (i < xt4 + w4 + 32) {
        int j2 = i - xt4 - w4;           // float4 index into biasPerm (o'=4*j2)
        int wn = j2 >> 4, mrow = j2 & 15;
        float4 v;
        v.x = bias[wn * 64 + 0 * 16 + mrow];
        v.y = bias[wn * 64 + 1 * 16 + mrow];
        v.z = bias[wn * 64 + 2 * 16 + mrow];
        v.w = bias[wn * 64 + 3 * 16 + mrow];
        reinterpret_cast<float4*>(biasPerm)[j2] = v;
    } else if (i < xt4 + w4 + 48) {
        int t = i - xt4 - w4 - 32;       // Y zero row: 16 x int4 = 256 B
        reinterpret_cast<int4*>(Yz)[t] = make_int4(0, 0, 0, 0);
    } else {
        int e = i - (xt4 + w4 + 48);
        if (e < E) {
            int j = jl[e], kk = kc[e];
            maskB[(size_t)kk * Mpad + j] = 1;
            if (e >= eg) {               // remainder bucket-fill
                int ii = ih[e];
                int off = (kk * Mpad + j) * 128;   // [K][Mpad][128] row offset
                int pos = atomicAdd(&counts[ii], 1);
                if (pos < CAP) {
                    bucket[(size_t)ii * CAP + pos] = off;
                } else {
                    int o = atomicAdd(ovf_cnt, 1);
                    if (o < OVF_MAX) { ovf_list[2 * o] = ii; ovf_list[2 * o + 1] = off; }
                }
            }
        }
    }
}

// ---------------- GEMM: Y[kcell][m] = X[m,:] * W[kcell]^T -------------------
// R9: BM=64 retile of the verified R6/R8 schedule. sA 16KB + sB 32KB = 48KB
// -> 3 blocks/CU (12 waves/CU, +50% occupancy vs the 64KB 2-block config
// that was stuck at OccupancyPercent~20 with nothing saturated). Per-block
// phases halve; block count doubles (more cross-block overlap of staging,
// MFMA and store-drain). Schedule/waits identical in structure; counts
// rescaled: prologue vmcnt(4), mid-loop vmcnt(9|8) (8 staging oldest,
// bucket + <=8 epilogue stores younger -> staging retired, stores in flight).
__global__ __launch_bounds__(256, 3) void gemm_xw(
    const _Float16* __restrict__ Xh,   // [Mpad][128]
    const _Float16* __restrict__ Wh,   // [K][128][128]  (o-major, c contiguous)
    _Float16* __restrict__ Y,          // [K][Mpad][128] (permuted rows)
    const unsigned char* __restrict__ maskB, // used-cell bytes, idx = kcell*Mpad+m
    int Mpad, int KD,                  // KD = K/3 (y-blocks per m-tile)
    const int* __restrict__ ih, const int* __restrict__ jl,
    const int* __restrict__ kc,
    int* __restrict__ counts, int* __restrict__ bucket,
    int* __restrict__ ovf_cnt, int* __restrict__ ovf_list, int eg) {
    __shared__ ushort sA[64 * 128];    // 16 KB
    __shared__ ushort sB[128 * 128];   // 32 KB
    const int tid = threadIdx.x;

    // ---- bijective XCD-chunked swizzle (m204) -----------------------------
    const int nwg = gridDim.x;
    const int bid = blockIdx.x;
    const int q = nwg >> 3, r = nwg & 7;
    const int xcd = bid & 7, idx = bid >> 3;
    const int wg = (xcd < r) ? xcd * (q + 1) + idx
                             : r * (q + 1) + (xcd - r) * q + idx;
    const int mtile = wg / KD;
    const int ky = wg - mtile * KD;
    const int m0 = mtile * 64;
    const int kc0 = ky * 3;

    // ---- stage A (4 iters) + B(kc0) (8 iters) -----------------------------
    const ushort* Ag = (const ushort*)Xh + (size_t)m0 * 128;
#pragma unroll
    for (int it = 0; it < 4; ++it) {
        int p = it * 256 + tid;
        int row = p >> 4, cpos = p & 15;
        int csrc = cpos ^ (row & 15);   // XOR swizzle keeps ds_read_b128 conflict-free
        __builtin_amdgcn_global_load_lds(
            (const __attribute__((address_space(1))) void*)(Ag + row * 128 + csrc * 8),
            (__attribute__((address_space(3))) void*)(&sA[row * 128 + cpos * 8]), 16, 0, 0);
    }
    {
        const ushort* Bg = (const ushort*)Wh + (size_t)kc0 * 128 * 128;
#pragma unroll
        for (int it = 0; it < 8; ++it) {
            int p = it * 256 + tid;
            int row = p >> 4, cpos = p & 15;
            int csrc = cpos ^ (row & 15);
            __builtin_amdgcn_global_load_lds(
                (const __attribute__((address_space(1))) void*)(Bg + row * 128 + csrc * 8),
                (__attribute__((address_space(3))) void*)(&sB[row * 128 + cpos * 8]), 16, 0, 0);
        }
    }
    __builtin_amdgcn_sched_barrier(0);   // pin: all 12 staging ops issued above

    // ---- bucket-fill issue: 3 loads + 1 atomic per thread (uniform) -------
    const bool hasE = (bid * 256) < eg;  // eg multiple of 256 -> block-uniform
    int i0 = 0, off0 = 0, pos0 = CAP;
    if (hasE) {
        int e = bid * 256 + tid;
        i0 = ih[e];
        off0 = (kc[e] * Mpad + jl[e]) * 128;
        pos0 = atomicAdd(&counts[i0], 1);
        __builtin_amdgcn_sched_barrier(0);
        asm volatile("s_waitcnt vmcnt(4)" ::: "memory");   // staging done; atomic in flight
    } else {
        __builtin_amdgcn_sched_barrier(0);
        asm volatile("s_waitcnt vmcnt(0)" ::: "memory");
    }
    __builtin_amdgcn_sched_barrier(0);
    __builtin_amdgcn_s_barrier();        // raw: no vmcnt(0) drain of the atomic
    __builtin_amdgcn_sched_barrier(0);

    const int lane = tid & 63;
    const int wid = tid >> 6;
    const int wm = wid & 1, wn = wid >> 1;   // 2x2 wave quadrants of 32x64
    const int mrow = lane & 15;
    const int g = lane >> 4;

    for (int kk = 0; kk < 3; ++kk) {
        f32x4 acc[2][4] = {};
#pragma unroll
        for (int kb = 0; kb < 4; ++kb) {
            half8 af[2], bf[4];
            const int cpos8 = ((kb * 4 + g) ^ mrow) * 8;
#pragma unroll
            for (int t = 0; t < 2; ++t) {
                int ra = wm * 32 + t * 16 + mrow;
                af[t] = *reinterpret_cast<const half8*>(&sA[ra * 128 + cpos8]);
            }
#pragma unroll
            for (int t = 0; t < 4; ++t) {
                int rb = wn * 64 + t * 16 + mrow;
                bf[t] = *reinterpret_cast<const half8*>(&sB[rb * 128 + cpos8]);
            }
#pragma unroll
            for (int mt = 0; mt < 2; ++mt)
#pragma unroll
                for (int nt = 0; nt < 4; ++nt)
                    acc[mt][nt] = __builtin_amdgcn_mfma_f32_16x16x32_f16(
                        af[mt], bf[nt], acc[mt][nt], 0, 0, 0);
        }
        if (kk < 2) {
            // raw barrier: compiler's lgkmcnt waits before the MFMAs above
            // guarantee every wave's sB ds_reads retired; no vmcnt drain needed.
            __builtin_amdgcn_s_barrier();
            __builtin_amdgcn_sched_barrier(0);
            const ushort* Bg = (const ushort*)Wh + (size_t)(kc0 + kk + 1) * 128 * 128;
#pragma unroll
            for (int it = 0; it < 8; ++it) {     // 8 staging loads (oldest)
                int p = it * 256 + tid;
                int row = p >> 4, cpos = p & 15;
                int csrc = cpos ^ (row & 15);
                __builtin_amdgcn_global_load_lds(
                    (const __attribute__((address_space(1))) void*)(Bg + row * 128 + csrc * 8),
                    (__attribute__((address_space(3))) void*)(&sB[row * 128 + cpos * 8]), 16, 0, 0);
            }
            __builtin_amdgcn_sched_barrier(0);
        }
        if (kk == 0 && hasE) {                   // consume atomic result
            if (pos0 < CAP) {
                bucket[(size_t)i0 * CAP + pos0] = off0;
            } else {
                int o = atomicAdd(ovf_cnt, 1);
                if (o < OVF_MAX) { ovf_list[2 * o] = i0; ovf_list[2 * o + 1] = off0; }
            }
        }
        // ---- epilogue: masked 8B NT stores; per (mt,r) 16 lanes = 128B ----
        const unsigned char* mBp = maskB + (size_t)(kc0 + kk) * Mpad + m0 + wm * 32;
        _Float16* Yt = Y + ((size_t)(kc0 + kk) * Mpad + m0) * 128 + wn * 64 + mrow * 4;
#pragma unroll
        for (int mt = 0; mt < 2; ++mt) {
            unsigned mw = *reinterpret_cast<const unsigned*>(mBp + mt * 16 + g * 4);
            if (mw) {
#pragma unroll
                for (int r = 0; r < 4; ++r) {
                    if ((mw >> (8 * r)) & 0xFFu) {
                        int row = wm * 32 + mt * 16 + g * 4 + r;
                        half4v hv;
#pragma unroll
                        for (int nt = 0; nt < 4; ++nt) hv[nt] = (_Float16)acc[mt][nt][r];
                        __builtin_nontemporal_store(
                            hv, reinterpret_cast<half4v*>(Yt + (size_t)row * 128));
                    }
                }
            }
        }
        __builtin_amdgcn_sched_barrier(0);
        if (kk == 0) {
            if (hasE) { asm volatile("s_waitcnt vmcnt(9)" ::: "memory"); }
            else      { asm volatile("s_waitcnt vmcnt(8)" ::: "memory"); }
            __builtin_amdgcn_sched_barrier(0);
            __builtin_amdgcn_s_barrier();
            __builtin_amdgcn_sched_barrier(0);
        } else if (kk == 1) {
            asm volatile("s_waitcnt vmcnt(8)" ::: "memory");
            __builtin_amdgcn_sched_barrier(0);
            __builtin_amdgcn_s_barrier();
            __builtin_amdgcn_sched_barrier(0);
        }
        // kk==2: fall through; endpgm drains outstanding stores
    }
}

// ---------------- gather: out[i] = bias + sum_{e in bucket[i]} Y[off_e] -----
// 4 points per wave, 16 lanes x half8 per row; unroll-8 for loads in flight
// (padding rounds hit the L1-cached zero row -> nearly free).
__global__ __launch_bounds__(256) void gather_out(
    const _Float16* __restrict__ Y, const int* __restrict__ counts,
    const int* __restrict__ bucket, const float* __restrict__ biasPerm,
    float* __restrict__ out, int Nhigh, int zoff) {
    int wave = (blockIdx.x * blockDim.x + threadIdx.x) >> 6;
    int lane = threadIdx.x & 63;
    int p = lane >> 4;                  // point within wave
    int sub = lane & 15;                // 16B piece within row
    int i = wave * 4 + p;
    bool act = i < Nhigh;
    int iC = act ? i : 0;
    int nb = counts[iC];
    if (nb > CAP) nb = CAP;
    const int* bk = bucket + (size_t)iC * CAP;
    int offsA = bk[sub];                // slots 0..15 across the quarter
    int offsB = bk[sub + 16];           // slots 16..31
    float4 b0 = reinterpret_cast<const float4*>(biasPerm)[sub * 2];
    float4 b1 = reinterpret_cast<const float4*>(biasPerm)[sub * 2 + 1];
    float acc[8] = {b0.x, b0.y, b0.z, b0.w, b1.x, b1.y, b1.z, b1.w};

    int nmax = nb;
    nmax = max(nmax, __shfl_xor(nmax, 16));
    nmax = max(nmax, __shfl_xor(nmax, 32));

    for (int e0 = 0; e0 < nmax; e0 += 8) {
#pragma unroll
        for (int u = 0; u < 8; ++u) {
            int e = e0 + u;                           // wave-uniform
            int off = (e < 16) ? __shfl(offsA, p * 16 + (e & 15))
                               : __shfl(offsB, p * 16 + (e & 15));
            bool valid = act && (e < nb);
            off = valid ? off : zoff;                 // zero row
            half8 h = *reinterpret_cast<const half8*>(Y + (size_t)off + sub * 8);
#pragma unroll
            for (int t = 0; t < 8; ++t) acc[t] += (float)h[t];
        }
    }
    if (act) {
        // channels o = obase+16b and o+1 are t=b and t=b+4 -> 8B stores
        float* op = out + (size_t)i * 128;
        int obase = (sub >> 3) * 64 + (sub & 7) * 2;
#pragma unroll
        for (int b = 0; b < 4; ++b) {
            f32x2 v; v[0] = acc[b]; v[1] = acc[b + 4];
            __builtin_nontemporal_store(
                v, reinterpret_cast<f32x2*>(op + obase + 16 * b));
        }
    }
}

// ---------------- rare overflow application (normally 0 entries) ------------
__global__ void apply_overflow(const int* __restrict__ ovf_cnt, const int* __restrict__ ovf_list,
                               const _Float16* __restrict__ Y, float* __restrict__ out) {
    int n = *ovf_cnt;
    if (n > OVF_MAX) n = OVF_MAX;
    int lane = threadIdx.x & 63;
    int w = threadIdx.x >> 6;        // 4 waves, 1 block
    int o0p = 2 * lane, o1p = 2 * lane + 1;
    int o0 = (o0p >> 6) * 64 + (o0p & 3) * 16 + ((o0p >> 2) & 15);
    int o1 = (o1p >> 6) * 64 + (o1p & 3) * 16 + ((o1p >> 2) & 15);
    for (int o = w; o < n; o += 4) {
        int i = ovf_list[2 * o], off = ovf_list[2 * o + 1];
        half2v h = *reinterpret_cast<const half2v*>(Y + (size_t)off + lane * 2);
        float* dst = out + (size_t)i * 128;
        unsafeAtomicAdd(dst + o0, (float)h[0]);
        unsafeAtomicAdd(dst + o1, (float)h[1]);
    }
}

// ---------------- tier-3 fallback: direct per-edge matvec -------------------
__global__ void fallback_edge(const float* __restrict__ x, const float* __restrict__ w,
                              const int* __restrict__ ih, const int* __restrict__ jl,
                              const int* __restrict__ kc, float* __restrict__ out, int E) {
    int e = blockIdx.x;
    if (e >= E) return;
    int lane = threadIdx.x;   // 64 threads
    int i = ih[e], j = jl[e], k = kc[e];
    const float* xr = x + (size_t)j * 128;
    const float* wk = w + (size_t)k * 128 * 128;
    float s0 = 0.f, s1 = 0.f;
    for (int c = 0; c < 128; ++c) {
        float xv = xr[c];
        s0 += wk[(size_t)lane * 128 + c] * xv;
        s1 += wk[(size_t)(lane + 64) * 128 + c] * xv;
    }
    unsafeAtomicAdd(&out[(size_t)i * 128 + lane], s0);
    unsafeAtomicAdd(&out[(size_t)i * 128 + 64 + lane], s1);
}

extern "C" void kernel_launch(void* const* d_in, const int* in_sizes, int n_in,
                              void* d_out, int out_size, void* d_ws, size_t ws_size,
                              hipStream_t stream) {
    const float* x    = (const float*)d_in[0];
    const float* w    = (const float*)d_in[1];
    const float* bias = (const float*)d_in[2];
    const int*   ih   = (const int*)d_in[3];
    const int*   jl   = (const int*)d_in[4];
    const int*   kc   = (const int*)d_in[5];
    float* out = (float*)d_out;

    const int C = 128;
    const int Nlow = in_sizes[0] / C;
    const int K = in_sizes[1] / (C * C);
    const int E = in_sizes[3];
    const int Nhigh = out_size / C;

    const int mtiles = (Nlow + 63) / 64;      // BM = 64
    const int Mpad = mtiles * 64;

    // ---- workspace layout -------------------------------------------------
    size_t off = 0;
    auto alloc = [&](size_t bytes) { size_t o = off; off = (off + bytes + 255) & ~(size_t)255; return o; };
    size_t xh_off   = alloc((size_t)Mpad * C * 2);
    size_t wh_off   = alloc((size_t)K * C * C * 2);
    size_t bp_off   = alloc((size_t)C * 4);                  // permuted bias
    size_t cnt_off  = alloc(((size_t)Nhigh + 1) * 4 + (size_t)Mpad * K); // counts+ovf+byte mask
    size_t ovl_off  = alloc((size_t)OVF_MAX * 2 * 4);
    size_t bkt_off  = alloc((size_t)Nhigh * CAP * 4);
    size_t y_off    = alloc(((size_t)K * Mpad * C + C) * 2); // [K][Mpad][128] + zero row
    size_t need_sort = off;

    _Float16* Xh = (_Float16*)((char*)d_ws + xh_off);
    _Float16* Wh = (_Float16*)((char*)d_ws + wh_off);
    float* biasPerm = (float*)((char*)d_ws + bp_off);
    int* counts  = (int*)((char*)d_ws + cnt_off);
    int* ovf_cnt = counts + Nhigh;
    unsigned char* maskB = (unsigned char*)(counts + Nhigh + 1);
    int* ovf_lst = (int*)((char*)d_ws + ovl_off);
    int* bucket  = (int*)((char*)d_ws + bkt_off);
    _Float16* Y  = (_Float16*)((char*)d_ws + y_off);
    const int zoff = K * Mpad * C;                           // zero-row offset (halfwords)

    if (ws_size >= need_sort && (K % 3) == 0) {
        int xv4 = Nlow * C / 4, xt4 = Mpad * C / 4;
        int w4 = K * C * C / 4;
        int KD = K / 3;
        int nwg = mtiles * KD;
        long long cap256 = (long long)nwg * 256;
        int eg = (E < cap256) ? (E & ~255) : (int)cap256;   // gemm-handled edges [0,eg)

        // counts + ovf + byte mask are contiguous -> one async memset
        size_t nzb = ((size_t)Nhigh + 1) * 4 + (size_t)Mpad * K;
        hipMemsetAsync(counts, 0, nzb, stream);

        int totalCvt = xt4 + w4 + 48 + E;
        cvt_mask<<<(totalCvt + 255) / 256, 256, 0, stream>>>(
            x, w, bias, Xh, Wh, biasPerm, Y + (size_t)zoff,
            ih, jl, kc, maskB, counts, bucket, ovf_cnt, ovf_lst,
            Mpad, xv4, xt4, w4, E, eg);

        gemm_xw<<<nwg, 256, 0, stream>>>(
            Xh, Wh, Y, maskB, Mpad, KD,
            ih, jl, kc, counts, bucket, ovf_cnt, ovf_lst, eg);

        gather_out<<<(Nhigh + 15) / 16, 256, 0, stream>>>(
            Y, counts, bucket, biasPerm, out, Nhigh, zoff);
        apply_overflow<<<1, 256, 0, stream>>>(ovf_cnt, ovf_lst, Y, out);
    } else {
        int n4out = out_size / 4;
        init_bias<<<(n4out + 255) / 256, 256, 0, stream>>>(out, bias, n4out);
        fallback_edge<<<E, 64, 0, stream>>>(x, w, ih, jl, kc, out, E);
    }
}